// Round 1
// baseline (566.318 us; speedup 1.0000x reference)
//
#include <hip/hip_runtime.h>

#define CIN   256
#define COUT  256
#define HH    64
#define WW    64
#define KTOT  2304      // CIN * 9
#define KC    32        // K-chunk
#define NCHUNK 72       // KTOT / KC
#define PIX   64        // pixels per block = one image row
#define WROW  260       // w_lds row stride in floats (16B-aligned, bank-offset 4/row)
#define AROW  72        // a_lds row stride in floats (16B-aligned, bank-offset 8/row)

__global__ __launch_bounds__(256) void deform_conv_kernel(
    const float* __restrict__ x,      // (8, 256, 64, 64)
    const float* __restrict__ off,    // (8, 18, 64, 64)
    const float* __restrict__ wgt,    // (256, 256, 3, 3)
    const float* __restrict__ bias,   // (256,)
    float* __restrict__ out)          // (8, 256, 64, 64)
{
    __shared__ float  w_lds[KC][WROW];
    __shared__ float  a_lds[KC][AROW];
    __shared__ int4   pidx[9][PIX];
    __shared__ float4 pwgt[9][PIX];

    const int tx  = threadIdx.x;
    const int blk = blockIdx.x;       // 512 blocks
    const int b   = blk >> 6;         // batch
    const int u   = blk & 63;         // output row

    // ---- precompute bilinear params for 64 pixels x 9 taps ----
    for (int item = tx; item < 9 * PIX; item += 256) {
        const int t = item >> 6;          // tap 0..8 (k*3+l)
        const int p = item & 63;          // pixel = output col v
        const int k = t / 3;
        const int l = t - 3 * k;
        // offset channel layout: (KH, KW, 2) -> dy at 2t, dx at 2t+1
        const float dy = off[((b * 18 + 2 * t    ) << 12) + u * 64 + p];
        const float dx = off[((b * 18 + 2 * t + 1) << 12) + u * 64 + p];
        const float py = dy + (float)(u - 1 + k);
        const float px = dx + (float)(p - 1 + l);
        const float y0f = floorf(py);
        const float x0f = floorf(px);
        const float wy = py - y0f;
        const float wx = px - x0f;
        const int y0 = (int)y0f, x0 = (int)x0f;
        const int y1 = y0 + 1,   x1 = x0 + 1;
        const bool vy0 = (y0 >= 0) && (y0 < HH);
        const bool vy1 = (y1 >= 0) && (y1 < HH);
        const bool vx0 = (x0 >= 0) && (x0 < WW);
        const bool vx1 = (x1 >= 0) && (x1 < WW);
        const int cy0 = min(max(y0, 0), HH - 1);
        const int cy1 = min(max(y1, 0), HH - 1);
        const int cx0 = min(max(x0, 0), WW - 1);
        const int cx1 = min(max(x1, 0), WW - 1);
        int4 id;
        id.x = cy0 * WW + cx0;
        id.y = cy0 * WW + cx1;
        id.z = cy1 * WW + cx0;
        id.w = cy1 * WW + cx1;
        float4 w4;
        w4.x = (1.f - wy) * (1.f - wx) * ((vy0 && vx0) ? 1.f : 0.f);
        w4.y = (1.f - wy) * wx         * ((vy0 && vx1) ? 1.f : 0.f);
        w4.z = wy * (1.f - wx)         * ((vy1 && vx0) ? 1.f : 0.f);
        w4.w = wy * wx                 * ((vy1 && vx1) ? 1.f : 0.f);
        pidx[t][p] = id;
        pwgt[t][p] = w4;
    }

    const int og = tx & 31;   // cout group: couts og*8 .. og*8+7
    const int pg = tx >> 5;   // pixel group: pixels pg*8 .. pg*8+7

    float acc[8][8];
    #pragma unroll
    for (int j = 0; j < 8; ++j)
        #pragma unroll
        for (int q = 0; q < 8; ++q) acc[j][q] = 0.f;

    __syncthreads();

    for (int kb = 0; kb < NCHUNK; ++kb) {
        const int k0 = kb * KC;

        // ---- stage weight chunk, transposed to [kk][o] ----
        #pragma unroll
        for (int it = 0; it < 8; ++it) {
            const int item = it * 256 + tx;
            const int o  = item >> 3;        // 0..255
            const int jj = item & 7;         // float4 index in the 32-float row
            const float4 v = *(const float4*)&wgt[o * KTOT + k0 + jj * 4];
            w_lds[jj * 4 + 0][o] = v.x;
            w_lds[jj * 4 + 1][o] = v.y;
            w_lds[jj * 4 + 2][o] = v.z;
            w_lds[jj * 4 + 3][o] = v.w;
        }

        // ---- stage sampled im2col chunk [kk][pixel] ----
        #pragma unroll
        for (int it = 0; it < 8; ++it) {
            const int item = it * 256 + tx;
            const int kk = item >> 6;        // 0..31
            const int p  = item & 63;        // pixel
            const int kg = k0 + kk;
            const int c  = kg / 9;           // compiler magic-mul
            const int t  = kg - 9 * c;
            const float* plane = x + ((b * CIN + c) << 12);
            const int4   id = pidx[t][p];
            const float4 w4 = pwgt[t][p];
            float v = w4.x * plane[id.x];
            v += w4.y * plane[id.y];
            v += w4.z * plane[id.z];
            v += w4.w * plane[id.w];
            a_lds[kk][p] = v;
        }
        __syncthreads();

        // ---- register-blocked GEMM: 8 couts x 8 pixels per thread ----
        #pragma unroll 2
        for (int kk = 0; kk < KC; ++kk) {
            const float4 w0 = *(const float4*)&w_lds[kk][og * 8];
            const float4 w1 = *(const float4*)&w_lds[kk][og * 8 + 4];
            const float4 a0 = *(const float4*)&a_lds[kk][pg * 8];
            const float4 a1 = *(const float4*)&a_lds[kk][pg * 8 + 4];
            const float wv[8] = {w0.x, w0.y, w0.z, w0.w, w1.x, w1.y, w1.z, w1.w};
            const float av[8] = {a0.x, a0.y, a0.z, a0.w, a1.x, a1.y, a1.z, a1.w};
            #pragma unroll
            for (int j = 0; j < 8; ++j)
                #pragma unroll
                for (int q = 0; q < 8; ++q)
                    acc[j][q] += wv[j] * av[q];
        }
        __syncthreads();
    }

    // ---- epilogue: bias + store ----
    const int vb = pg * 8;
    #pragma unroll
    for (int j = 0; j < 8; ++j) {
        const int o = og * 8 + j;
        const float bv = bias[o];
        float4 r0, r1;
        r0.x = acc[j][0] + bv; r0.y = acc[j][1] + bv;
        r0.z = acc[j][2] + bv; r0.w = acc[j][3] + bv;
        r1.x = acc[j][4] + bv; r1.y = acc[j][5] + bv;
        r1.z = acc[j][6] + bv; r1.w = acc[j][7] + bv;
        float* op = out + ((b * COUT + o) << 12) + u * 64 + vb;
        *(float4*)op       = r0;
        *(float4*)(op + 4) = r1;
    }
}

extern "C" void kernel_launch(void* const* d_in, const int* in_sizes, int n_in,
                              void* d_out, int out_size, void* d_ws, size_t ws_size,
                              hipStream_t stream) {
    const float* x    = (const float*)d_in[0];
    const float* off  = (const float*)d_in[1];
    const float* wgt  = (const float*)d_in[2];
    const float* bias = (const float*)d_in[3];
    float* out = (float*)d_out;
    deform_conv_kernel<<<dim3(8 * 64), dim3(256), 0, stream>>>(x, off, wgt, bias, out);
}

// Round 2
// 133.330 us; speedup vs baseline: 4.2475x; 4.2475x over previous
//
#include <hip/hip_runtime.h>
#include <hip/hip_bf16.h>
#include <stdint.h>

typedef __attribute__((ext_vector_type(8))) short s16x8;
typedef __attribute__((ext_vector_type(4))) float f32x4;

// ---------------- workspace layout (bytes) ----------------
#define XT_OFF   0u           // xt[b][yx][c] bf16 : 8*4096*256*2 = 16,777,216
#define WT_OFF   16777216u    // Wt tiled bf16     : 72*256*64B   =  1,179,648
#define PW_OFF   17956864u    // pwgt float4       : 8*9*4096*16  =  4,718,592
#define PI_OFF   22675456u    // pidx ushort4      : 8*9*4096*8   =  2,359,296
#define WS_NEED  25034752u

static __device__ __forceinline__ uint16_t f2bf(float f) {
    __hip_bfloat16 h = __float2bfloat16(f);
    uint16_t u;
    __builtin_memcpy(&u, &h, 2);
    return u;
}
static __device__ __forceinline__ float bflo(uint32_t w) { return __uint_as_float(w << 16); }
static __device__ __forceinline__ float bfhi(uint32_t w) { return __uint_as_float(w & 0xffff0000u); }

// ---------- preprocess 1: x (8,256,64,64) f32 -> xt[b][yx][c] bf16 ----------
__global__ __launch_bounds__(256) void k_transpose_x(const float* __restrict__ x,
                                                     uint16_t* __restrict__ xt) {
    __shared__ float tile[64][65];
    const int blk = blockIdx.x;            // 8*64*4 = 2048
    const int b   = blk >> 8;
    const int yxt = (blk >> 2) & 63;
    const int ct  = blk & 3;
    const int yx0 = yxt << 6, c0 = ct << 6;
    const int tx  = threadIdx.x;
    const int ty  = tx >> 6, lx = tx & 63;
    #pragma unroll
    for (int i = 0; i < 16; ++i) {
        const int c = (i << 2) + ty;
        tile[c][lx] = x[(size_t)((b * 256 + c0 + c) << 12) + yx0 + lx];
    }
    __syncthreads();
    const int cpr = lx & 31;
    #pragma unroll
    for (int i = 0; i < 8; ++i) {
        const int r = (ty << 1) + (lx >> 5) + (i << 3);
        const uint32_t lo = f2bf(tile[2 * cpr][r]);
        const uint32_t hi = f2bf(tile[2 * cpr + 1][r]);
        *(uint32_t*)&xt[(size_t)(b * 4096 + yx0 + r) * 256 + c0 + 2 * cpr] = lo | (hi << 16);
    }
}

// ---------- preprocess 2: weight (256,256,3,3) f32 -> Wt[kb][o][32] bf16, swizzled ----------
__global__ __launch_bounds__(256) void k_prep_w(const float* __restrict__ wgt,
                                                uint16_t* __restrict__ wt) {
    const int o = blockIdx.x;      // 256
    const int c = threadIdx.x;     // 256 (Cin)
    #pragma unroll
    for (int t = 0; t < 9; ++t) {
        const float v = wgt[(size_t)o * 2304 + c * 9 + t];
        const int kb = t * 8 + (c >> 5);
        const int kk = c & 31;
        const uint32_t byte = (uint32_t)kb * 16384u + (uint32_t)o * 64u
            + (uint32_t)(((((kk >> 3) ^ ((o >> 1) & 3)) << 4)) | ((kk & 7) << 1));
        wt[byte >> 1] = f2bf(v);
    }
}

// ---------- preprocess 3: offsets -> bilinear params per (b,t,pixel) ----------
__global__ __launch_bounds__(256) void k_prep_params(const float* __restrict__ off,
                                                     float4* __restrict__ pw,
                                                     uint2* __restrict__ pi) {
    const int blk = blockIdx.x;            // 8*9*16 = 1152
    const int b = blk / 144;
    const int r = blk - b * 144;
    const int t = r >> 4;
    const int p = ((r & 15) << 8) + threadIdx.x;   // 0..4095
    const int u = p >> 6, v = p & 63;
    const int kh = t / 3, kw = t - 3 * kh;
    const float dy = off[(size_t)((b * 18 + 2 * t) << 12) + p];
    const float dx = off[(size_t)((b * 18 + 2 * t + 1) << 12) + p];
    const float py = dy + (float)(u - 1 + kh);
    const float px = dx + (float)(v - 1 + kw);
    const float y0f = floorf(py), x0f = floorf(px);
    const float wy = py - y0f, wx = px - x0f;
    const int y0 = (int)y0f, x0 = (int)x0f;
    const int y1 = y0 + 1, x1 = x0 + 1;
    const bool vy0 = (y0 >= 0) && (y0 < 64);
    const bool vy1 = (y1 >= 0) && (y1 < 64);
    const bool vx0 = (x0 >= 0) && (x0 < 64);
    const bool vx1 = (x1 >= 0) && (x1 < 64);
    const int cy0 = min(max(y0, 0), 63), cy1 = min(max(y1, 0), 63);
    const int cx0 = min(max(x0, 0), 63), cx1 = min(max(x1, 0), 63);
    float4 w4;
    w4.x = (1.f - wy) * (1.f - wx) * ((vy0 && vx0) ? 1.f : 0.f);
    w4.y = (1.f - wy) * wx         * ((vy0 && vx1) ? 1.f : 0.f);
    w4.z = wy * (1.f - wx)         * ((vy1 && vx0) ? 1.f : 0.f);
    w4.w = wy * wx                 * ((vy1 && vx1) ? 1.f : 0.f);
    uint2 id;
    id.x = (uint32_t)(cy0 * 64 + cx0) | ((uint32_t)(cy0 * 64 + cx1) << 16);
    id.y = (uint32_t)(cy1 * 64 + cx0) | ((uint32_t)(cy1 * 64 + cx1) << 16);
    const size_t o_ = (size_t)(b * 9 + t) * 4096 + p;
    pw[o_] = w4;
    pi[o_] = id;
}

// ---------- main: 256x128 block tile, 8 waves of 64x64, bf16 MFMA ----------
#define STAGE(KB, BF) do {                                                        \
    const int kb_ = (KB);                                                         \
    /* weights: 16KB linear DMA, 2x 1KB per wave */                               \
    {                                                                             \
        const char* gw = (const char*)wt + (size_t)kb_ * 16384u;                  \
        char* lw = (char*)&w_lds[BF][0];                                          \
        _Pragma("unroll")                                                         \
        for (int it = 0; it < 2; ++it) {                                          \
            const int seg = wv * 2 + it;                                          \
            __builtin_amdgcn_global_load_lds(                                     \
                (const __attribute__((address_space(1))) void*)(gw + seg * 1024 + lane * 16), \
                (__attribute__((address_space(3))) void*)(lw + seg * 1024),       \
                16, 0, 0);                                                        \
        }                                                                         \
    }                                                                             \
    /* im2col sample: 8 channels for pixel sp */                                  \
    {                                                                             \
        const int t_  = kb_ >> 3;                                                 \
        const int cg_ = ((kb_ & 7) << 5) + (cq << 3);                             \
        const size_t pb_ = (size_t)(b * 9 + t_) * 4096 + pg;                      \
        const float4 w4 = pw[pb_];                                                \
        const uint2  id = pi[pb_];                                                \
        const uint4 A  = *(const uint4*)(xb + (id.x & 0xffffu) * 256u + cg_);     \
        const uint4 Bv = *(const uint4*)(xb + (id.x >> 16)     * 256u + cg_);     \
        const uint4 Cv = *(const uint4*)(xb + (id.y & 0xffffu) * 256u + cg_);     \
        const uint4 Dv = *(const uint4*)(xb + (id.y >> 16)     * 256u + cg_);     \
        const uint32_t ax[4] = {A.x, A.y, A.z, A.w};                              \
        const uint32_t bx[4] = {Bv.x, Bv.y, Bv.z, Bv.w};                          \
        const uint32_t cx[4] = {Cv.x, Cv.y, Cv.z, Cv.w};                          \
        const uint32_t dx[4] = {Dv.x, Dv.y, Dv.z, Dv.w};                          \
        uint32_t pk[4];                                                           \
        _Pragma("unroll")                                                         \
        for (int j = 0; j < 4; ++j) {                                             \
            const float rlo = w4.x * bflo(ax[j]) + w4.y * bflo(bx[j])             \
                            + w4.z * bflo(cx[j]) + w4.w * bflo(dx[j]);            \
            const float rhi = w4.x * bfhi(ax[j]) + w4.y * bfhi(bx[j])             \
                            + w4.z * bfhi(cx[j]) + w4.w * bfhi(dx[j]);            \
            pk[j] = (uint32_t)f2bf(rlo) | ((uint32_t)f2bf(rhi) << 16);            \
        }                                                                         \
        uint4 P; P.x = pk[0]; P.y = pk[1]; P.z = pk[2]; P.w = pk[3];              \
        *(uint4*)((char*)&b_lds[BF][0] + sp * 64 + slot_w) = P;                   \
    }                                                                             \
} while (0)

__global__ __launch_bounds__(512, 2) void k_main(const uint16_t* __restrict__ xt,
                                                 const uint16_t* __restrict__ wt,
                                                 const float4* __restrict__ pw,
                                                 const uint2* __restrict__ pi,
                                                 const float* __restrict__ bias,
                                                 float* __restrict__ out) {
    __shared__ uint16_t w_lds[2][256 * 32];   // 2 x 16KB
    __shared__ uint16_t b_lds[2][128 * 32];   // 2 x 8KB

    const int orig = blockIdx.x;                      // 256 blocks
    const int bid  = (orig & 7) * 32 + (orig >> 3);   // XCD swizzle: one batch per XCD
    const int b    = bid >> 5;
    const int pix0 = (bid & 31) << 7;

    const int tx   = threadIdx.x;
    const int lane = tx & 63;
    const int wv   = tx >> 6;        // wave 0..7
    const int wc   = wv & 3;         // cout group (64 couts)
    const int wp   = wv >> 2;        // pixel group (64 pixels)
    const int l15  = lane & 15;
    const int kp   = lane >> 4;

    // sampling mapping: thread -> (pixel sp, channel-quad cq)
    const int sp   = tx & 127;
    const int cq   = tx >> 7;                       // 0..3 -> 8 channels each
    const int pg   = pix0 + sp;
    const int slot_w = (cq ^ ((sp >> 1) & 3)) << 4;

    // fragment read base byte-offsets (swizzle slot invariant in m/n since step=16 rows)
    const int ar    = wc * 64 + l15;
    const int a_off = ar * 64 + ((kp ^ ((ar >> 1) & 3)) << 4);
    const int br    = wp * 64 + l15;
    const int b_off = br * 64 + ((kp ^ ((br >> 1) & 3)) << 4);

    const uint16_t* xb = xt + (size_t)b * 4096 * 256;

    f32x4 acc[4][4];
    #pragma unroll
    for (int m = 0; m < 4; ++m)
        #pragma unroll
        for (int n = 0; n < 4; ++n) acc[m][n] = (f32x4){0.f, 0.f, 0.f, 0.f};

    STAGE(0, 0);

    #pragma unroll 2
    for (int kb = 0; kb < 72; ++kb) {
        const int bf = kb & 1;
        __syncthreads();
        if (kb < 71) {
            if (bf == 0) STAGE(kb + 1, 1); else STAGE(kb + 1, 0);
        }
        const char* wb = (const char*)&w_lds[bf][0];
        const char* bb = (const char*)&b_lds[bf][0];
        s16x8 afr[4], bfr[4];
        #pragma unroll
        for (int m = 0; m < 4; ++m) afr[m] = *(const s16x8*)(wb + a_off + m * 1024);
        #pragma unroll
        for (int n = 0; n < 4; ++n) bfr[n] = *(const s16x8*)(bb + b_off + n * 1024);
        #pragma unroll
        for (int m = 0; m < 4; ++m)
            #pragma unroll
            for (int n = 0; n < 4; ++n)
                acc[m][n] = __builtin_amdgcn_mfma_f32_16x16x32_bf16(afr[m], bfr[n], acc[m][n], 0, 0, 0);
    }

    // epilogue: bias + store
    #pragma unroll
    for (int m = 0; m < 4; ++m) {
        #pragma unroll
        for (int q = 0; q < 4; ++q) {
            const int o = wc * 64 + m * 16 + kp * 4 + q;
            const float bv = bias[o];
            float* orow = out + (((size_t)(b * 256 + o)) << 12) + pix0 + wp * 64;
            #pragma unroll
            for (int n = 0; n < 4; ++n)
                orow[n * 16 + l15] = acc[m][n][q] + bv;
        }
    }
}

// ================= fallback fp32 kernel (round-1, known-correct) =================
#define KTOT 2304
#define KCF  32
#define WROW 260
#define AROW 72

__global__ __launch_bounds__(256) void deform_conv_fallback(
    const float* __restrict__ x, const float* __restrict__ off,
    const float* __restrict__ wgt, const float* __restrict__ bias,
    float* __restrict__ out) {
    __shared__ float  w_lds[KCF][WROW];
    __shared__ float  a_lds[KCF][AROW];
    __shared__ int4   pidx[9][64];
    __shared__ float4 pwgt[9][64];
    const int tx = threadIdx.x;
    const int blk = blockIdx.x;
    const int b = blk >> 6, u = blk & 63;
    for (int item = tx; item < 9 * 64; item += 256) {
        const int t = item >> 6, p = item & 63;
        const int k = t / 3, l = t - 3 * k;
        const float dy = off[((b * 18 + 2 * t) << 12) + u * 64 + p];
        const float dx = off[((b * 18 + 2 * t + 1) << 12) + u * 64 + p];
        const float py = dy + (float)(u - 1 + k);
        const float px = dx + (float)(p - 1 + l);
        const float y0f = floorf(py), x0f = floorf(px);
        const float wy = py - y0f, wx = px - x0f;
        const int y0 = (int)y0f, x0 = (int)x0f, y1 = y0 + 1, x1 = x0 + 1;
        const bool vy0 = (y0 >= 0) && (y0 < 64), vy1 = (y1 >= 0) && (y1 < 64);
        const bool vx0 = (x0 >= 0) && (x0 < 64), vx1 = (x1 >= 0) && (x1 < 64);
        const int cy0 = min(max(y0, 0), 63), cy1 = min(max(y1, 0), 63);
        const int cx0 = min(max(x0, 0), 63), cx1 = min(max(x1, 0), 63);
        int4 id; id.x = cy0 * 64 + cx0; id.y = cy0 * 64 + cx1;
        id.z = cy1 * 64 + cx0; id.w = cy1 * 64 + cx1;
        float4 w4;
        w4.x = (1.f - wy) * (1.f - wx) * ((vy0 && vx0) ? 1.f : 0.f);
        w4.y = (1.f - wy) * wx * ((vy0 && vx1) ? 1.f : 0.f);
        w4.z = wy * (1.f - wx) * ((vy1 && vx0) ? 1.f : 0.f);
        w4.w = wy * wx * ((vy1 && vx1) ? 1.f : 0.f);
        pidx[t][p] = id; pwgt[t][p] = w4;
    }
    const int og = tx & 31, pgr = tx >> 5;
    float acc[8][8];
    #pragma unroll
    for (int j = 0; j < 8; ++j)
        #pragma unroll
        for (int q = 0; q < 8; ++q) acc[j][q] = 0.f;
    __syncthreads();
    for (int kb = 0; kb < 72; ++kb) {
        const int k0 = kb * KCF;
        #pragma unroll
        for (int it = 0; it < 8; ++it) {
            const int item = it * 256 + tx;
            const int o = item >> 3, jj = item & 7;
            const float4 v = *(const float4*)&wgt[o * KTOT + k0 + jj * 4];
            w_lds[jj * 4 + 0][o] = v.x; w_lds[jj * 4 + 1][o] = v.y;
            w_lds[jj * 4 + 2][o] = v.z; w_lds[jj * 4 + 3][o] = v.w;
        }
        #pragma unroll
        for (int it = 0; it < 8; ++it) {
            const int item = it * 256 + tx;
            const int kk = item >> 6, p = item & 63;
            const int kg = k0 + kk;
            const int c = kg / 9, t = kg - 9 * c;
            const float* plane = x + ((b * 256 + c) << 12);
            const int4 id = pidx[t][p];
            const float4 w4 = pwgt[t][p];
            float v = w4.x * plane[id.x] + w4.y * plane[id.y]
                    + w4.z * plane[id.z] + w4.w * plane[id.w];
            a_lds[kk][p] = v;
        }
        __syncthreads();
        #pragma unroll 2
        for (int kk = 0; kk < KCF; ++kk) {
            const float4 w0 = *(const float4*)&w_lds[kk][og * 8];
            const float4 w1 = *(const float4*)&w_lds[kk][og * 8 + 4];
            const float4 a0 = *(const float4*)&a_lds[kk][pgr * 8];
            const float4 a1 = *(const float4*)&a_lds[kk][pgr * 8 + 4];
            const float wv[8] = {w0.x, w0.y, w0.z, w0.w, w1.x, w1.y, w1.z, w1.w};
            const float av[8] = {a0.x, a0.y, a0.z, a0.w, a1.x, a1.y, a1.z, a1.w};
            #pragma unroll
            for (int j = 0; j < 8; ++j)
                #pragma unroll
                for (int q = 0; q < 8; ++q) acc[j][q] += wv[j] * av[q];
        }
        __syncthreads();
    }
    const int vb = pgr * 8;
    #pragma unroll
    for (int j = 0; j < 8; ++j) {
        const int o = og * 8 + j;
        const float bv = bias[o];
        float* op = out + ((b * 256 + o) << 12) + u * 64 + vb;
        float4 r0, r1;
        r0.x = acc[j][0] + bv; r0.y = acc[j][1] + bv; r0.z = acc[j][2] + bv; r0.w = acc[j][3] + bv;
        r1.x = acc[j][4] + bv; r1.y = acc[j][5] + bv; r1.z = acc[j][6] + bv; r1.w = acc[j][7] + bv;
        *(float4*)op = r0; *(float4*)(op + 4) = r1;
    }
}

extern "C" void kernel_launch(void* const* d_in, const int* in_sizes, int n_in,
                              void* d_out, int out_size, void* d_ws, size_t ws_size,
                              hipStream_t stream) {
    const float* x    = (const float*)d_in[0];
    const float* off  = (const float*)d_in[1];
    const float* wgt  = (const float*)d_in[2];
    const float* bias = (const float*)d_in[3];
    float* out = (float*)d_out;

    if (ws_size < WS_NEED) {
        deform_conv_fallback<<<dim3(512), dim3(256), 0, stream>>>(x, off, wgt, bias, out);
        return;
    }
    uint16_t* xt  = (uint16_t*)((char*)d_ws + XT_OFF);
    uint16_t* wtp = (uint16_t*)((char*)d_ws + WT_OFF);
    float4*   pwp = (float4*)((char*)d_ws + PW_OFF);
    uint2*    pip = (uint2*)((char*)d_ws + PI_OFF);

    k_transpose_x <<<dim3(2048), dim3(256), 0, stream>>>(x, xt);
    k_prep_w      <<<dim3(256),  dim3(256), 0, stream>>>(wgt, wtp);
    k_prep_params <<<dim3(1152), dim3(256), 0, stream>>>(off, pwp, pip);
    k_main        <<<dim3(256),  dim3(512), 0, stream>>>(xt, wtp, pwp, pip, bias, out);
}

// Round 3
// 100.295 us; speedup vs baseline: 5.6465x; 1.3294x over previous
//
#include <hip/hip_runtime.h>
#include <hip/hip_bf16.h>
#include <stdint.h>

typedef __attribute__((ext_vector_type(8))) short s16x8;
typedef __attribute__((ext_vector_type(4))) float f32x4;

// ---------------- workspace layout (bytes) ----------------
#define XT_OFF   0u           // xt[b][yx][c] bf16 : 8*4096*256*2 = 16,777,216
#define WT_OFF   16777216u    // Wt tiled bf16     : 72*256*64B   =  1,179,648
#define PW_OFF   17956864u    // pwgt float4       : 8*9*4096*16  =  4,718,592
#define PI_OFF   22675456u    // pidx packed       : 8*9*4096*8   =  2,359,296
#define WS_NEED  25034752u

static __device__ __forceinline__ uint16_t f2bf(float f) {
    __hip_bfloat16 h = __float2bfloat16(f);
    uint16_t u;
    __builtin_memcpy(&u, &h, 2);
    return u;
}
static __device__ __forceinline__ float bflo(uint32_t w) { return __uint_as_float(w << 16); }
static __device__ __forceinline__ float bfhi(uint32_t w) { return __uint_as_float(w & 0xffff0000u); }

// ---------- preprocess 1: x (8,256,64,64) f32 -> xt[b][yx][c] bf16 ----------
__global__ __launch_bounds__(256) void k_transpose_x(const float* __restrict__ x,
                                                     uint16_t* __restrict__ xt) {
    __shared__ float tile[64][65];
    const int blk = blockIdx.x;            // 8*64*4 = 2048
    const int b   = blk >> 8;
    const int yxt = (blk >> 2) & 63;
    const int ct  = blk & 3;
    const int yx0 = yxt << 6, c0 = ct << 6;
    const int tx  = threadIdx.x;
    const int ty  = tx >> 6, lx = tx & 63;
    #pragma unroll
    for (int i = 0; i < 16; ++i) {
        const int c = (i << 2) + ty;
        tile[c][lx] = x[(size_t)((b * 256 + c0 + c) << 12) + yx0 + lx];
    }
    __syncthreads();
    const int cpr = lx & 31;
    #pragma unroll
    for (int i = 0; i < 8; ++i) {
        const int r = (ty << 1) + (lx >> 5) + (i << 3);
        const uint32_t lo = f2bf(tile[2 * cpr][r]);
        const uint32_t hi = f2bf(tile[2 * cpr + 1][r]);
        *(uint32_t*)&xt[(size_t)(b * 4096 + yx0 + r) * 256 + c0 + 2 * cpr] = lo | (hi << 16);
    }
}

// ---------- preprocess 2: weight -> Wt[kb][o][32ch] bf16, A-frag swizzled ----------
__global__ __launch_bounds__(256) void k_prep_w(const float* __restrict__ wgt,
                                                uint16_t* __restrict__ wt) {
    const int o = blockIdx.x;      // 256
    const int c = threadIdx.x;     // 256 (Cin)
    #pragma unroll
    for (int t = 0; t < 9; ++t) {
        const float v = wgt[(size_t)o * 2304 + c * 9 + t];
        const int kb = t * 8 + (c >> 5);
        const int kk = c & 31;
        const uint32_t byte = (uint32_t)kb * 16384u + (uint32_t)o * 64u
            + (uint32_t)(((((kk >> 3) ^ ((o >> 1) & 3)) << 4)) | ((kk & 7) << 1));
        wt[byte >> 1] = f2bf(v);
    }
}

// ---------- preprocess 3: offsets -> bilinear params per (b,t,pixel) ----------
__global__ __launch_bounds__(256) void k_prep_params(const float* __restrict__ off,
                                                     float4* __restrict__ pw,
                                                     uint2* __restrict__ pi) {
    const int blk = blockIdx.x;            // 8*9*16 = 1152
    const int b = blk / 144;
    const int r = blk - b * 144;
    const int t = r >> 4;
    const int p = ((r & 15) << 8) + threadIdx.x;   // 0..4095
    const int u = p >> 6, v = p & 63;
    const int kh = t / 3, kw = t - 3 * kh;
    const float dy = off[(size_t)((b * 18 + 2 * t) << 12) + p];
    const float dx = off[(size_t)((b * 18 + 2 * t + 1) << 12) + p];
    const float py = dy + (float)(u - 1 + kh);
    const float px = dx + (float)(v - 1 + kw);
    const float y0f = floorf(py), x0f = floorf(px);
    const float wy = py - y0f, wx = px - x0f;
    const int y0 = (int)y0f, x0 = (int)x0f;
    const int y1 = y0 + 1, x1 = x0 + 1;
    const bool vy0 = (y0 >= 0) && (y0 < 64);
    const bool vy1 = (y1 >= 0) && (y1 < 64);
    const bool vx0 = (x0 >= 0) && (x0 < 64);
    const bool vx1 = (x1 >= 0) && (x1 < 64);
    const int cy0 = min(max(y0, 0), 63), cy1 = min(max(y1, 0), 63);
    const int cx0 = min(max(x0, 0), 63), cx1 = min(max(x1, 0), 63);
    float4 w4;
    w4.x = (1.f - wy) * (1.f - wx) * ((vy0 && vx0) ? 1.f : 0.f);
    w4.y = (1.f - wy) * wx         * ((vy0 && vx1) ? 1.f : 0.f);
    w4.z = wy * (1.f - wx)         * ((vy1 && vx0) ? 1.f : 0.f);
    w4.w = wy * wx                 * ((vy1 && vx1) ? 1.f : 0.f);
    uint2 id;
    id.x = (uint32_t)(cy0 * 64 + cx0) | ((uint32_t)(cy0 * 64 + cx1) << 16);
    id.y = (uint32_t)(cy1 * 64 + cx0) | ((uint32_t)(cy1 * 64 + cx1) << 16);
    const size_t o_ = (size_t)(b * 9 + t) * 4096 + p;
    pw[o_] = w4;
    pi[o_] = id;
}

// ---------- main: 256 Cout x 64 pix per block, per-tap wave-coherent staging ----------
__global__ __launch_bounds__(512, 4) void k_main(const uint16_t* __restrict__ xt,
                                                 const uint16_t* __restrict__ wt,
                                                 const float4* __restrict__ pw,
                                                 const uint2* __restrict__ pi,
                                                 const float* __restrict__ bias,
                                                 float* __restrict__ out) {
    __shared__ uint16_t w_lds[2][8192];      // 2 x 16KB weight double-buffer
    __shared__ uint16_t im2col[64 * 256];    // 32KB: [pix][256ch], slot-swizzled

    const int orig = blockIdx.x;                      // 512 blocks
    const int bid  = (orig & 7) * 64 + (orig >> 3);   // XCD swizzle: one batch/XCD
    const int b    = bid >> 6;
    const int pix0 = (bid & 63) << 6;

    const int tx   = threadIdx.x;
    const int lane = tx & 63;
    const int wv   = tx >> 6;        // wave 0..7
    const int wc   = wv & 3;         // cout quadrant (64 couts)
    const int wp   = wv >> 2;        // pixel half (32 pixels)
    const int l15  = lane & 15;
    const int kp   = lane >> 4;

    // A-frag read base (identical swizzle to k_prep_w layout; verified round 2)
    const int ar    = wc * 64 + l15;
    const int a_off = ar * 64 + ((kp ^ ((ar >> 1) & 3)) << 4);

    const uint16_t* xb = xt + (size_t)b * 4096 * 256;

    f32x4 acc[4][2];
    #pragma unroll
    for (int m = 0; m < 4; ++m)
        #pragma unroll
        for (int j = 0; j < 2; ++j) acc[m][j] = (f32x4){0.f, 0.f, 0.f, 0.f};

    for (int t = 0; t < 9; ++t) {
        __syncthreads();
        // W DMA for step 0 of this tap into buffer 0 (in flight during staging)
        {
            const char* gw = (const char*)wt + (size_t)(t * 8) * 16384u;
            char* lw = (char*)&w_lds[0][0];
            #pragma unroll
            for (int it = 0; it < 2; ++it) {
                const int seg = wv * 2 + it;
                __builtin_amdgcn_global_load_lds(
                    (const __attribute__((address_space(1))) void*)(gw + seg * 1024 + lane * 16),
                    (__attribute__((address_space(3))) void*)(lw + seg * 1024), 16, 0, 0);
            }
        }
        // ---- stage im2col for tap t: one pixel per wave-iteration, coalesced rows ----
        #pragma unroll
        for (int i = 0; i < 8; ++i) {
            const int lp = wv * 8 + i;             // local pixel 0..63
            const int uidx = __builtin_amdgcn_readfirstlane((b * 9 + t) * 4096 + pix0 + lp);
            const uint2  id = pi[uidx];            // wave-uniform -> scalar
            const float4 w4 = pw[uidx];
            const uint16_t* p00 = xb + (id.x & 0xffffu) * 256u;
            const uint16_t* p01 = xb + (id.x >> 16)     * 256u;
            const uint16_t* p10 = xb + (id.y & 0xffffu) * 256u;
            const uint16_t* p11 = xb + (id.y >> 16)     * 256u;
            const uint2 A  = *(const uint2*)(p00 + lane * 4);   // 512B coalesced / wave
            const uint2 Bv = *(const uint2*)(p01 + lane * 4);
            const uint2 Cv = *(const uint2*)(p10 + lane * 4);
            const uint2 Dv = *(const uint2*)(p11 + lane * 4);
            uint2 r;
            {
                const float lo = w4.x * bflo(A.x) + w4.y * bflo(Bv.x)
                               + w4.z * bflo(Cv.x) + w4.w * bflo(Dv.x);
                const float hi = w4.x * bfhi(A.x) + w4.y * bfhi(Bv.x)
                               + w4.z * bfhi(Cv.x) + w4.w * bfhi(Dv.x);
                r.x = (uint32_t)f2bf(lo) | ((uint32_t)f2bf(hi) << 16);
            }
            {
                const float lo = w4.x * bflo(A.y) + w4.y * bflo(Bv.y)
                               + w4.z * bflo(Cv.y) + w4.w * bflo(Dv.y);
                const float hi = w4.x * bfhi(A.y) + w4.y * bfhi(Bv.y)
                               + w4.z * bfhi(Cv.y) + w4.w * bfhi(Dv.y);
                r.y = (uint32_t)f2bf(lo) | ((uint32_t)f2bf(hi) << 16);
            }
            // swizzled write: 16B slot index ^= (pix & 7); conflict-free (per-wave row)
            const int slot = (lane >> 1) ^ (lp & 7);
            *(uint2*)((char*)im2col + lp * 512 + slot * 16 + (lane & 1) * 8) = r;
        }
        __syncthreads();

        // ---- inner 8 K-steps: W dbuf + MFMA ----
        #pragma unroll
        for (int s = 0; s < 8; ++s) {
            const int kb = t * 8 + s;
            if (kb + 1 < 72) {
                const char* gw = (const char*)wt + (size_t)(kb + 1) * 16384u;
                char* lw = (char*)&w_lds[(s + 1) & 1][0];
                #pragma unroll
                for (int it = 0; it < 2; ++it) {
                    const int seg = wv * 2 + it;
                    __builtin_amdgcn_global_load_lds(
                        (const __attribute__((address_space(1))) void*)(gw + seg * 1024 + lane * 16),
                        (__attribute__((address_space(3))) void*)(lw + seg * 1024), 16, 0, 0);
                }
            }
            const char* wb = (const char*)&w_lds[s & 1][0];
            s16x8 afr[4], bfr[2];
            #pragma unroll
            for (int m = 0; m < 4; ++m) afr[m] = *(const s16x8*)(wb + a_off + m * 1024);
            #pragma unroll
            for (int j = 0; j < 2; ++j) {
                const int pix  = wp * 32 + j * 16 + l15;
                const int boff = pix * 512 + (((s * 4 + kp) ^ (l15 & 7)) << 4);
                bfr[j] = *(const s16x8*)((const char*)im2col + boff);
            }
            #pragma unroll
            for (int m = 0; m < 4; ++m)
                #pragma unroll
                for (int j = 0; j < 2; ++j)
                    acc[m][j] = __builtin_amdgcn_mfma_f32_16x16x32_bf16(afr[m], bfr[j], acc[m][j], 0, 0, 0);
            __syncthreads();
        }
    }

    // ---- epilogue: bias + store ----
    #pragma unroll
    for (int m = 0; m < 4; ++m) {
        #pragma unroll
        for (int q = 0; q < 4; ++q) {
            const int o = wc * 64 + m * 16 + kp * 4 + q;
            const float bv = bias[o];
            float* orow = out + (((size_t)(b * 256 + o)) << 12) + pix0 + wp * 32;
            #pragma unroll
            for (int j = 0; j < 2; ++j)
                orow[j * 16 + l15] = acc[m][j][q] + bv;
        }
    }
}

// ================= fallback fp32 kernel (round-1, known-correct) =================
#define KTOT 2304
#define KCF  32
#define WROW 260
#define AROW 72

__global__ __launch_bounds__(256) void deform_conv_fallback(
    const float* __restrict__ x, const float* __restrict__ off,
    const float* __restrict__ wgt, const float* __restrict__ bias,
    float* __restrict__ out) {
    __shared__ float  w_lds[KCF][WROW];
    __shared__ float  a_lds[KCF][AROW];
    __shared__ int4   pidx[9][64];
    __shared__ float4 pwgt[9][64];
    const int tx = threadIdx.x;
    const int blk = blockIdx.x;
    const int b = blk >> 6, u = blk & 63;
    for (int item = tx; item < 9 * 64; item += 256) {
        const int t = item >> 6, p = item & 63;
        const int k = t / 3, l = t - 3 * k;
        const float dy = off[((b * 18 + 2 * t) << 12) + u * 64 + p];
        const float dx = off[((b * 18 + 2 * t + 1) << 12) + u * 64 + p];
        const float py = dy + (float)(u - 1 + k);
        const float px = dx + (float)(p - 1 + l);
        const float y0f = floorf(py), x0f = floorf(px);
        const float wy = py - y0f, wx = px - x0f;
        const int y0 = (int)y0f, x0 = (int)x0f, y1 = y0 + 1, x1 = x0 + 1;
        const bool vy0 = (y0 >= 0) && (y0 < 64), vy1 = (y1 >= 0) && (y1 < 64);
        const bool vx0 = (x0 >= 0) && (x0 < 64), vx1 = (x1 >= 0) && (x1 < 64);
        const int cy0 = min(max(y0, 0), 63), cy1 = min(max(y1, 0), 63);
        const int cx0 = min(max(x0, 0), 63), cx1 = min(max(x1, 0), 63);
        int4 id; id.x = cy0 * 64 + cx0; id.y = cy0 * 64 + cx1;
        id.z = cy1 * 64 + cx0; id.w = cy1 * 64 + cx1;
        float4 w4;
        w4.x = (1.f - wy) * (1.f - wx) * ((vy0 && vx0) ? 1.f : 0.f);
        w4.y = (1.f - wy) * wx * ((vy0 && vx1) ? 1.f : 0.f);
        w4.z = wy * (1.f - wx) * ((vy1 && vx0) ? 1.f : 0.f);
        w4.w = wy * wx * ((vy1 && vx1) ? 1.f : 0.f);
        pidx[t][p] = id; pwgt[t][p] = w4;
    }
    const int og = tx & 31, pgr = tx >> 5;
    float acc[8][8];
    #pragma unroll
    for (int j = 0; j < 8; ++j)
        #pragma unroll
        for (int q = 0; q < 8; ++q) acc[j][q] = 0.f;
    __syncthreads();
    for (int kb = 0; kb < 72; ++kb) {
        const int k0 = kb * KCF;
        #pragma unroll
        for (int it = 0; it < 8; ++it) {
            const int item = it * 256 + tx;
            const int o = item >> 3, jj = item & 7;
            const float4 v = *(const float4*)&wgt[o * KTOT + k0 + jj * 4];
            w_lds[jj * 4 + 0][o] = v.x; w_lds[jj * 4 + 1][o] = v.y;
            w_lds[jj * 4 + 2][o] = v.z; w_lds[jj * 4 + 3][o] = v.w;
        }
        #pragma unroll
        for (int it = 0; it < 8; ++it) {
            const int item = it * 256 + tx;
            const int kk = item >> 6, p = item & 63;
            const int kg = k0 + kk;
            const int c = kg / 9, t = kg - 9 * c;
            const float* plane = x + ((b * 256 + c) << 12);
            const int4 id = pidx[t][p];
            const float4 w4 = pwgt[t][p];
            float v = w4.x * plane[id.x] + w4.y * plane[id.y]
                    + w4.z * plane[id.z] + w4.w * plane[id.w];
            a_lds[kk][p] = v;
        }
        __syncthreads();
        #pragma unroll 2
        for (int kk = 0; kk < KCF; ++kk) {
            const float4 w0 = *(const float4*)&w_lds[kk][og * 8];
            const float4 w1 = *(const float4*)&w_lds[kk][og * 8 + 4];
            const float4 a0 = *(const float4*)&a_lds[kk][pgr * 8];
            const float4 a1 = *(const float4*)&a_lds[kk][pgr * 8 + 4];
            const float wv[8] = {w0.x, w0.y, w0.z, w0.w, w1.x, w1.y, w1.z, w1.w};
            const float av[8] = {a0.x, a0.y, a0.z, a0.w, a1.x, a1.y, a1.z, a1.w};
            #pragma unroll
            for (int j = 0; j < 8; ++j)
                #pragma unroll
                for (int q = 0; q < 8; ++q) acc[j][q] += wv[j] * av[q];
        }
        __syncthreads();
    }
    const int vb = pgr * 8;
    #pragma unroll
    for (int j = 0; j < 8; ++j) {
        const int o = og * 8 + j;
        const float bv = bias[o];
        float* op = out + ((b * 256 + o) << 12) + u * 64 + vb;
        float4 r0, r1;
        r0.x = acc[j][0] + bv; r0.y = acc[j][1] + bv; r0.z = acc[j][2] + bv; r0.w = acc[j][3] + bv;
        r1.x = acc[j][4] + bv; r1.y = acc[j][5] + bv; r1.z = acc[j][6] + bv; r1.w = acc[j][7] + bv;
        *(float4*)op = r0; *(float4*)(op + 4) = r1;
    }
}

extern "C" void kernel_launch(void* const* d_in, const int* in_sizes, int n_in,
                              void* d_out, int out_size, void* d_ws, size_t ws_size,
                              hipStream_t stream) {
    const float* x    = (const float*)d_in[0];
    const float* off  = (const float*)d_in[1];
    const float* wgt  = (const float*)d_in[2];
    const float* bias = (const float*)d_in[3];
    float* out = (float*)d_out;

    if (ws_size < WS_NEED) {
        deform_conv_fallback<<<dim3(512), dim3(256), 0, stream>>>(x, off, wgt, bias, out);
        return;
    }
    uint16_t* xt  = (uint16_t*)((char*)d_ws + XT_OFF);
    uint16_t* wtp = (uint16_t*)((char*)d_ws + WT_OFF);
    float4*   pwp = (float4*)((char*)d_ws + PW_OFF);
    uint2*    pip = (uint2*)((char*)d_ws + PI_OFF);

    k_transpose_x <<<dim3(2048), dim3(256), 0, stream>>>(x, xt);
    k_prep_w      <<<dim3(256),  dim3(256), 0, stream>>>(wgt, wtp);
    k_prep_params <<<dim3(1152), dim3(256), 0, stream>>>(off, pwp, pip);
    k_main        <<<dim3(512),  dim3(512), 0, stream>>>(xt, wtp, pwp, pip, bias, out);
}

// Round 4
// 98.863 us; speedup vs baseline: 5.7283x; 1.0145x over previous
//
#include <hip/hip_runtime.h>
#include <hip/hip_bf16.h>
#include <stdint.h>

typedef __attribute__((ext_vector_type(8))) short s16x8;
typedef __attribute__((ext_vector_type(4))) float f32x4;

// ---------------- workspace layout (bytes) ----------------
#define XT_OFF   0u           // xt[b][yx][c] bf16 : 8*4096*256*2 = 16,777,216
#define WT_OFF   16777216u    // Wt tiled bf16     : 72*256*64B   =  1,179,648
#define PW_OFF   17956864u    // pwgt float4       : 8*9*4096*16  =  4,718,592
#define PI_OFF   22675456u    // pidx packed       : 8*9*4096*8   =  2,359,296
#define WS_NEED  25034752u

static __device__ __forceinline__ uint16_t f2bf(float f) {
    __hip_bfloat16 h = __float2bfloat16(f);
    uint16_t u;
    __builtin_memcpy(&u, &h, 2);
    return u;
}
static __device__ __forceinline__ float bflo(uint32_t w) { return __uint_as_float(w << 16); }
static __device__ __forceinline__ float bfhi(uint32_t w) { return __uint_as_float(w & 0xffff0000u); }

// ---------- preprocess 1: x (8,256,64,64) f32 -> xt[b][yx][c] bf16 ----------
__global__ __launch_bounds__(256) void k_transpose_x(const float* __restrict__ x,
                                                     uint16_t* __restrict__ xt) {
    __shared__ float tile[64][65];
    const int blk = blockIdx.x;            // 8*64*4 = 2048
    const int b   = blk >> 8;
    const int yxt = (blk >> 2) & 63;
    const int ct  = blk & 3;
    const int yx0 = yxt << 6, c0 = ct << 6;
    const int tx  = threadIdx.x;
    const int ty  = tx >> 6, lx = tx & 63;
    #pragma unroll
    for (int i = 0; i < 16; ++i) {
        const int c = (i << 2) + ty;
        tile[c][lx] = x[(size_t)((b * 256 + c0 + c) << 12) + yx0 + lx];
    }
    __syncthreads();
    const int cpr = lx & 31;
    #pragma unroll
    for (int i = 0; i < 8; ++i) {
        const int r = (ty << 1) + (lx >> 5) + (i << 3);
        const uint32_t lo = f2bf(tile[2 * cpr][r]);
        const uint32_t hi = f2bf(tile[2 * cpr + 1][r]);
        *(uint32_t*)&xt[(size_t)(b * 4096 + yx0 + r) * 256 + c0 + 2 * cpr] = lo | (hi << 16);
    }
}

// ---------- preprocess 2: weight -> Wt[kb][o][32ch] bf16, A-frag swizzled ----------
__global__ __launch_bounds__(256) void k_prep_w(const float* __restrict__ wgt,
                                                uint16_t* __restrict__ wt) {
    const int o = blockIdx.x;      // 256
    const int c = threadIdx.x;     // 256 (Cin)
    #pragma unroll
    for (int t = 0; t < 9; ++t) {
        const float v = wgt[(size_t)o * 2304 + c * 9 + t];
        const int kb = t * 8 + (c >> 5);
        const int kk = c & 31;
        const uint32_t byte = (uint32_t)kb * 16384u + (uint32_t)o * 64u
            + (uint32_t)(((((kk >> 3) ^ ((o >> 1) & 3)) << 4)) | ((kk & 7) << 1));
        wt[byte >> 1] = f2bf(v);
    }
}

// ---------- preprocess 3: offsets -> bilinear params per (b,t,pixel) ----------
__global__ __launch_bounds__(256) void k_prep_params(const float* __restrict__ off,
                                                     float4* __restrict__ pw,
                                                     uint2* __restrict__ pi) {
    const int blk = blockIdx.x;            // 8*9*16 = 1152
    const int b = blk / 144;
    const int r = blk - b * 144;
    const int t = r >> 4;
    const int p = ((r & 15) << 8) + threadIdx.x;   // 0..4095
    const int u = p >> 6, v = p & 63;
    const int kh = t / 3, kw = t - 3 * kh;
    const float dy = off[(size_t)((b * 18 + 2 * t) << 12) + p];
    const float dx = off[(size_t)((b * 18 + 2 * t + 1) << 12) + p];
    const float py = dy + (float)(u - 1 + kh);
    const float px = dx + (float)(v - 1 + kw);
    const float y0f = floorf(py), x0f = floorf(px);
    const float wy = py - y0f, wx = px - x0f;
    const int y0 = (int)y0f, x0 = (int)x0f;
    const int y1 = y0 + 1, x1 = x0 + 1;
    const bool vy0 = (y0 >= 0) && (y0 < 64);
    const bool vy1 = (y1 >= 0) && (y1 < 64);
    const bool vx0 = (x0 >= 0) && (x0 < 64);
    const bool vx1 = (x1 >= 0) && (x1 < 64);
    const int cy0 = min(max(y0, 0), 63), cy1 = min(max(y1, 0), 63);
    const int cx0 = min(max(x0, 0), 63), cx1 = min(max(x1, 0), 63);
    float4 w4;
    w4.x = (1.f - wy) * (1.f - wx) * ((vy0 && vx0) ? 1.f : 0.f);
    w4.y = (1.f - wy) * wx         * ((vy0 && vx1) ? 1.f : 0.f);
    w4.z = wy * (1.f - wx)         * ((vy1 && vx0) ? 1.f : 0.f);
    w4.w = wy * wx                 * ((vy1 && vx1) ? 1.f : 0.f);
    uint2 id;
    id.x = (uint32_t)(cy0 * 64 + cx0) | ((uint32_t)(cy0 * 64 + cx1) << 16);
    id.y = (uint32_t)(cy1 * 64 + cx0) | ((uint32_t)(cy1 * 64 + cx1) << 16);
    const size_t o_ = (size_t)(b * 9 + t) * 4096 + p;
    pw[o_] = w4;
    pi[o_] = id;
}

// ---------- main: 256 Cout x 64 pix per block; 3-buf counted-vmcnt W pipeline ----------
#define W_DMA(KB, BUF) do {                                                       \
    const char* gw_ = (const char*)wt + (size_t)(KB) * 16384u;                    \
    char* lw_ = (char*)&w_lds[BUF][0];                                            \
    _Pragma("unroll")                                                             \
    for (int it_ = 0; it_ < 2; ++it_) {                                           \
        const int seg_ = wv * 2 + it_;                                            \
        __builtin_amdgcn_global_load_lds(                                         \
            (const __attribute__((address_space(1))) void*)(gw_ + seg_ * 1024 + lane * 16), \
            (__attribute__((address_space(3))) void*)(lw_ + seg_ * 1024), 16, 0, 0); \
    }                                                                             \
} while (0)

__global__ __launch_bounds__(512, 4) void k_main(const uint16_t* __restrict__ xt,
                                                 const uint16_t* __restrict__ wt,
                                                 const float4* __restrict__ pw,
                                                 const uint2* __restrict__ pi,
                                                 const float* __restrict__ bias,
                                                 float* __restrict__ out) {
    __shared__ uint16_t w_lds[3][8192];      // 3 x 16KB weight ring
    __shared__ uint16_t im2col[64 * 256];    // 32KB: [pix][256ch], slot-swizzled

    const int orig = blockIdx.x;                      // 512 blocks
    const int bid  = (orig & 7) * 64 + (orig >> 3);   // XCD swizzle: one batch/XCD
    const int b    = bid >> 6;
    const int pix0 = (bid & 63) << 6;

    const int tx   = threadIdx.x;
    const int lane = tx & 63;
    const int wv   = tx >> 6;        // wave 0..7
    const int wc   = wv & 3;         // cout quadrant (64 couts)
    const int wp   = wv >> 2;        // pixel half (32 pixels)
    const int l15  = lane & 15;
    const int kp   = lane >> 4;

    // A-frag read base (matches k_prep_w swizzle; verified rounds 2-3)
    const int ar    = wc * 64 + l15;
    const int a_off = ar * 64 + ((kp ^ ((ar >> 1) & 3)) << 4);

    const uint16_t* xb = xt + (size_t)b * 4096 * 256;

    f32x4 acc[4][2];
    #pragma unroll
    for (int m = 0; m < 4; ++m)
        #pragma unroll
        for (int j = 0; j < 2; ++j) acc[m][j] = (f32x4){0.f, 0.f, 0.f, 0.f};

    // prologue: prime W pipeline (kb=0,1)
    W_DMA(0, 0);
    W_DMA(1, 1);

    for (int t = 0; t < 9; ++t) {
        __syncthreads();   // prev-tap im2col reads done; (drains vmcnt: bufs kb,kb+1 ready)
        // ---- stage im2col for tap t: one pixel per wave-iteration, coalesced rows ----
        #pragma unroll
        for (int i = 0; i < 8; ++i) {
            const int lp = wv * 8 + i;             // local pixel 0..63
            const int uidx = __builtin_amdgcn_readfirstlane((b * 9 + t) * 4096 + pix0 + lp);
            const uint2  id = pi[uidx];            // wave-uniform -> scalar
            const float4 w4 = pw[uidx];
            const uint16_t* p00 = xb + (id.x & 0xffffu) * 256u;
            const uint16_t* p01 = xb + (id.x >> 16)     * 256u;
            const uint16_t* p10 = xb + (id.y & 0xffffu) * 256u;
            const uint16_t* p11 = xb + (id.y >> 16)     * 256u;
            const uint2 A  = *(const uint2*)(p00 + lane * 4);   // 512B coalesced / wave
            const uint2 Bv = *(const uint2*)(p01 + lane * 4);
            const uint2 Cv = *(const uint2*)(p10 + lane * 4);
            const uint2 Dv = *(const uint2*)(p11 + lane * 4);
            uint2 r;
            {
                const float lo = w4.x * bflo(A.x) + w4.y * bflo(Bv.x)
                               + w4.z * bflo(Cv.x) + w4.w * bflo(Dv.x);
                const float hi = w4.x * bfhi(A.x) + w4.y * bfhi(Bv.x)
                               + w4.z * bfhi(Cv.x) + w4.w * bfhi(Dv.x);
                r.x = (uint32_t)f2bf(lo) | ((uint32_t)f2bf(hi) << 16);
            }
            {
                const float lo = w4.x * bflo(A.y) + w4.y * bflo(Bv.y)
                               + w4.z * bflo(Cv.y) + w4.w * bflo(Dv.y);
                const float hi = w4.x * bfhi(A.y) + w4.y * bfhi(Bv.y)
                               + w4.z * bfhi(Cv.y) + w4.w * bfhi(Dv.y);
                r.y = (uint32_t)f2bf(lo) | ((uint32_t)f2bf(hi) << 16);
            }
            const int slot = (lane >> 1) ^ (lp & 7);
            *(uint2*)((char*)im2col + lp * 512 + slot * 16 + (lane & 1) * 8) = r;
        }
        __syncthreads();

        // ---- inner 8 K-steps: counted-vmcnt W ring + MFMA, no drains ----
        #pragma unroll
        for (int s = 0; s < 8; ++s) {
            const int kb = t * 8 + s;
            // own buf[kb] loads done (newer kb+1 may stay in flight); prev ds_reads consumed
            if (t == 8 && s == 7) asm volatile("s_waitcnt vmcnt(0) lgkmcnt(0)" ::: "memory");
            else                  asm volatile("s_waitcnt vmcnt(2) lgkmcnt(0)" ::: "memory");
            __builtin_amdgcn_s_barrier();      // wait-then-barrier: all waves' buf[kb] ready
            __builtin_amdgcn_sched_barrier(0);
            // issue kb+2 AFTER barrier: target buf (kb+2)%3 == (kb-1)%3, reads of it
            // completed before this barrier (lgkmcnt(0) at step head)
            if (kb + 2 < 72) {
                const int ib = (kb + 2) % 3;
                W_DMA(kb + 2, ib);
            }
            const int cb = kb % 3;
            const char* wb = (const char*)&w_lds[cb][0];
            s16x8 afr[4], bfr[2];
            #pragma unroll
            for (int m = 0; m < 4; ++m) afr[m] = *(const s16x8*)(wb + a_off + m * 1024);
            #pragma unroll
            for (int j = 0; j < 2; ++j) {
                const int pix  = wp * 32 + j * 16 + l15;
                const int boff = pix * 512 + (((s * 4 + kp) ^ (l15 & 7)) << 4);
                bfr[j] = *(const s16x8*)((const char*)im2col + boff);
            }
            __builtin_amdgcn_s_setprio(1);
            #pragma unroll
            for (int m = 0; m < 4; ++m)
                #pragma unroll
                for (int j = 0; j < 2; ++j)
                    acc[m][j] = __builtin_amdgcn_mfma_f32_16x16x32_bf16(afr[m], bfr[j], acc[m][j], 0, 0, 0);
            __builtin_amdgcn_s_setprio(0);
        }
    }

    // ---- epilogue: bias + store ----
    #pragma unroll
    for (int m = 0; m < 4; ++m) {
        #pragma unroll
        for (int q = 0; q < 4; ++q) {
            const int o = wc * 64 + m * 16 + kp * 4 + q;
            const float bv = bias[o];
            float* orow = out + (((size_t)(b * 256 + o)) << 12) + pix0 + wp * 32;
            #pragma unroll
            for (int j = 0; j < 2; ++j)
                orow[j * 16 + l15] = acc[m][j][q] + bv;
        }
    }
}

// ================= fallback fp32 kernel (round-1, known-correct) =================
#define KTOT 2304
#define KCF  32
#define WROW 260
#define AROW 72

__global__ __launch_bounds__(256) void deform_conv_fallback(
    const float* __restrict__ x, const float* __restrict__ off,
    const float* __restrict__ wgt, const float* __restrict__ bias,
    float* __restrict__ out) {
    __shared__ float  w_lds[KCF][WROW];
    __shared__ float  a_lds[KCF][AROW];
    __shared__ int4   pidx[9][64];
    __shared__ float4 pwgt[9][64];
    const int tx = threadIdx.x;
    const int blk = blockIdx.x;
    const int b = blk >> 6, u = blk & 63;
    for (int item = tx; item < 9 * 64; item += 256) {
        const int t = item >> 6, p = item & 63;
        const int k = t / 3, l = t - 3 * k;
        const float dy = off[((b * 18 + 2 * t) << 12) + u * 64 + p];
        const float dx = off[((b * 18 + 2 * t + 1) << 12) + u * 64 + p];
        const float py = dy + (float)(u - 1 + k);
        const float px = dx + (float)(p - 1 + l);
        const float y0f = floorf(py), x0f = floorf(px);
        const float wy = py - y0f, wx = px - x0f;
        const int y0 = (int)y0f, x0 = (int)x0f, y1 = y0 + 1, x1 = x0 + 1;
        const bool vy0 = (y0 >= 0) && (y0 < 64), vy1 = (y1 >= 0) && (y1 < 64);
        const bool vx0 = (x0 >= 0) && (x0 < 64), vx1 = (x1 >= 0) && (x1 < 64);
        const int cy0 = min(max(y0, 0), 63), cy1 = min(max(y1, 0), 63);
        const int cx0 = min(max(x0, 0), 63), cx1 = min(max(x1, 0), 63);
        int4 id; id.x = cy0 * 64 + cx0; id.y = cy0 * 64 + cx1;
        id.z = cy1 * 64 + cx0; id.w = cy1 * 64 + cx1;
        float4 w4;
        w4.x = (1.f - wy) * (1.f - wx) * ((vy0 && vx0) ? 1.f : 0.f);
        w4.y = (1.f - wy) * wx * ((vy0 && vx1) ? 1.f : 0.f);
        w4.z = wy * (1.f - wx) * ((vy1 && vx0) ? 1.f : 0.f);
        w4.w = wy * wx * ((vy1 && vx1) ? 1.f : 0.f);
        pidx[t][p] = id; pwgt[t][p] = w4;
    }
    const int og = tx & 31, pgr = tx >> 5;
    float acc[8][8];
    #pragma unroll
    for (int j = 0; j < 8; ++j)
        #pragma unroll
        for (int q = 0; q < 8; ++q) acc[j][q] = 0.f;
    __syncthreads();
    for (int kb = 0; kb < 72; ++kb) {
        const int k0 = kb * KCF;
        #pragma unroll
        for (int it = 0; it < 8; ++it) {
            const int item = it * 256 + tx;
            const int o = item >> 3, jj = item & 7;
            const float4 v = *(const float4*)&wgt[o * KTOT + k0 + jj * 4];
            w_lds[jj * 4 + 0][o] = v.x; w_lds[jj * 4 + 1][o] = v.y;
            w_lds[jj * 4 + 2][o] = v.z; w_lds[jj * 4 + 3][o] = v.w;
        }
        #pragma unroll
        for (int it = 0; it < 8; ++it) {
            const int item = it * 256 + tx;
            const int kk = item >> 6, p = item & 63;
            const int kg = k0 + kk;
            const int c = kg / 9, t = kg - 9 * c;
            const float* plane = x + ((b * 256 + c) << 12);
            const int4 id = pidx[t][p];
            const float4 w4 = pwgt[t][p];
            float v = w4.x * plane[id.x] + w4.y * plane[id.y]
                    + w4.z * plane[id.z] + w4.w * plane[id.w];
            a_lds[kk][p] = v;
        }
        __syncthreads();
        #pragma unroll 2
        for (int kk = 0; kk < KCF; ++kk) {
            const float4 w0 = *(const float4*)&w_lds[kk][og * 8];
            const float4 w1 = *(const float4*)&w_lds[kk][og * 8 + 4];
            const float4 a0 = *(const float4*)&a_lds[kk][pgr * 8];
            const float4 a1 = *(const float4*)&a_lds[kk][pgr * 8 + 4];
            const float wv[8] = {w0.x, w0.y, w0.z, w0.w, w1.x, w1.y, w1.z, w1.w};
            const float av[8] = {a0.x, a0.y, a0.z, a0.w, a1.x, a1.y, a1.z, a1.w};
            #pragma unroll
            for (int j = 0; j < 8; ++j)
                #pragma unroll
                for (int q = 0; q < 8; ++q) acc[j][q] += wv[j] * av[q];
        }
        __syncthreads();
    }
    const int vb = pgr * 8;
    #pragma unroll
    for (int j = 0; j < 8; ++j) {
        const int o = og * 8 + j;
        const float bv = bias[o];
        float* op = out + ((b * 256 + o) << 12) + u * 64 + vb;
        float4 r0, r1;
        r0.x = acc[j][0] + bv; r0.y = acc[j][1] + bv; r0.z = acc[j][2] + bv; r0.w = acc[j][3] + bv;
        r1.x = acc[j][4] + bv; r1.y = acc[j][5] + bv; r1.z = acc[j][6] + bv; r1.w = acc[j][7] + bv;
        *(float4*)op = r0; *(float4*)(op + 4) = r1;
    }
}

extern "C" void kernel_launch(void* const* d_in, const int* in_sizes, int n_in,
                              void* d_out, int out_size, void* d_ws, size_t ws_size,
                              hipStream_t stream) {
    const float* x    = (const float*)d_in[0];
    const float* off  = (const float*)d_in[1];
    const float* wgt  = (const float*)d_in[2];
    const float* bias = (const float*)d_in[3];
    float* out = (float*)d_out;

    if (ws_size < WS_NEED) {
        deform_conv_fallback<<<dim3(512), dim3(256), 0, stream>>>(x, off, wgt, bias, out);
        return;
    }
    uint16_t* xt  = (uint16_t*)((char*)d_ws + XT_OFF);
    uint16_t* wtp = (uint16_t*)((char*)d_ws + WT_OFF);
    float4*   pwp = (float4*)((char*)d_ws + PW_OFF);
    uint2*    pip = (uint2*)((char*)d_ws + PI_OFF);

    k_transpose_x <<<dim3(2048), dim3(256), 0, stream>>>(x, xt);
    k_prep_w      <<<dim3(256),  dim3(256), 0, stream>>>(wgt, wtp);
    k_prep_params <<<dim3(1152), dim3(256), 0, stream>>>(off, pwp, pip);
    k_main        <<<dim3(512),  dim3(512), 0, stream>>>(xt, wtp, pwp, pip, bias, out);
}